// Round 3
// baseline (667.417 us; speedup 1.0000x reference)
//
#include <hip/hip_runtime.h>

#define Bsz 64
#define Tsz 2048
#define Esz 512
#define Asz 128
#define Rsz 1024
#define KP  576      // 512 (E) + 62 conv taps + 2 zero pad
#define TILE_M 32
#define NTILES 4
#define CHUNK (TILE_M*NTILES)   // 128 t-rows per block

typedef __bf16 bf16;
typedef __bf16 bf16x8 __attribute__((ext_vector_type(8)));
typedef __bf16 bf16x4 __attribute__((ext_vector_type(4)));
typedef __bf16 bf16x2 __attribute__((ext_vector_type(2)));
typedef float  f32x4  __attribute__((ext_vector_type(4)));

// Wext layout: [72 kgroups][128 a][8] bf16 -> element (a,k) at [k>>3][a][k&7].
// B-fragment load for (acol, kbase=kg*8) = 16 consecutive bytes at ((kg*128)+acol)*8,
// consecutive acol -> consecutive 16B -> coalesced.

// ---------------- prep ----------------
__global__ __launch_bounds__(256) void prep_kernel(
    const float* __restrict__ Wmem, const float* __restrict__ convw,
    const float* __restrict__ Wloc, const float* __restrict__ ah,
    const float* __restrict__ Wq, bf16* __restrict__ Wext,
    float* __restrict__ pq)
{
  __shared__ f32x4 red[256];
  int blk = blockIdx.x, tid = threadIdx.x;
  if (blk < 128) {
    int a = blk;
    #pragma unroll
    for (int e = tid; e < Esz; e += 256)
      Wext[(size_t)(e >> 3)*(Asz*8) + a*8 + (e & 7)] = (bf16)Wmem[e*Asz + a];
  } else if (blk < 160) {
    int idx = (blk - 128)*256 + tid;      // 8192 = 128 a x 64 j
    int a = idx >> 6, j = idx & 63;
    float u = 0.f;
    if (j < 62) {
      int c  = (j < 31) ? 0 : 1;
      int kk = (j < 31) ? j : j - 31;
      #pragma unroll
      for (int f = 0; f < 32; ++f)
        u += convw[f*62 + c*31 + kk] * Wloc[f*Asz + a];
    }
    Wext[(size_t)(64 + (j >> 3))*(Asz*8) + a*8 + (j & 7)] = (bf16)u;
  } else {
    int b  = blk - 160;
    int cg = tid & 31;                    // 4 columns each
    int kg = tid >> 5;                    // 8 k-groups x 128 rows
    const float* ahb = ah + (size_t)b*Rsz;
    f32x4 s = (f32x4){0.f,0.f,0.f,0.f};
    int r0 = kg*128;
    for (int r = r0; r < r0 + 128; ++r) {
      float av = ahb[r];
      f32x4 wq = *(const f32x4*)&Wq[r*Asz + cg*4];
      s += av * wq;
    }
    red[tid] = s;
    __syncthreads();
    if (tid < 32) {
      f32x4 tot = red[tid];
      #pragma unroll
      for (int g = 1; g < 8; ++g) tot += red[g*32 + tid];
      *(f32x4*)&pq[b*Asz + tid*4] = tot;
    }
  }
}

// ---------------- main fused kernel ----------------
__global__ __launch_bounds__(256, 4) void attn_main(
    const float* __restrict__ memory, const float* __restrict__ awcat,
    const int* __restrict__ mask, const bf16* __restrict__ Wext,
    const float* __restrict__ pq, const float* __restrict__ vw,
    const float* __restrict__ vb, float* __restrict__ out,
    float* __restrict__ ws_align)
{
  __shared__ bf16  Afull[TILE_M * KP];   // 36864 B, XOR-chunk swizzled
  __shared__ float s_pq[Asz];
  __shared__ float s_vw[Asz];
  __shared__ float s_ebuf[TILE_M];
  __shared__ float s_align[TILE_M];

  int tid = threadIdx.x;
  int b     = blockIdx.x >> 4;           // 16 chunks per batch row
  int tbase = (blockIdx.x & 15) * CHUNK;

  const float4* memv = (const float4*)memory + (size_t)(b*Tsz + tbase)*(Esz/4);
  const float*  aw   = awcat + (size_t)b*2*Tsz;

  if (tid < Asz) { s_pq[tid] = pq[b*Asz + tid]; s_vw[tid] = vw[tid]; }

  // prologue: issue tile-0 HBM loads
  float4 pre[16];
  #pragma unroll
  for (int p = 0; p < 16; ++p) {
    int i = tid + p*256;
    pre[p] = memv[(i >> 7)*128 + (i & 127)];
  }

  int w = tid >> 6, l = tid & 63;
  int quad = l >> 4, lrow = l & 15;
  float outa0 = 0.f, outa1 = 0.f;
  int k0 = tid * 2;

  #pragma unroll 1
  for (int j = 0; j < NTILES; ++j) {
    if (tid < TILE_M) s_ebuf[tid] = 0.f;
    // convert prefetched tile -> bf16 LDS (waits on pre's vmcnt)
    #pragma unroll
    for (int p = 0; p < 16; ++p) {
      int i = tid + p*256;
      int r = i >> 7, c4 = i & 127;
      int k = c4 * 4;
      int sw = (k >> 3) ^ (r & 7);
      bf16x4 pk; pk[0]=(bf16)pre[p].x; pk[1]=(bf16)pre[p].y; pk[2]=(bf16)pre[p].z; pk[3]=(bf16)pre[p].w;
      *(bf16x4*)&Afull[r*KP + sw*8 + (k & 7)] = pk;
    }
    // im2col'd aw window -> K columns 512..575
    #pragma unroll
    for (int i2 = tid; i2 < TILE_M*64; i2 += 256) {
      int r = i2 >> 6, jj = i2 & 63;
      float val = 0.f;
      if (jj < 62) {
        int c  = (jj < 31) ? 0 : 1;
        int kk = (jj < 31) ? jj : jj - 31;
        int t  = tbase + j*TILE_M + r + kk - 15;
        if (t >= 0 && t < Tsz) val = aw[c*Tsz + t];
      }
      int k = Esz + jj;
      int sw = (k >> 3) ^ (r & 7);
      Afull[r*KP + sw*8 + (k & 7)] = (bf16)val;
    }
    __syncthreads();

    // issue NEXT tile's HBM loads now: in flight during GEMM + epilogue
    if (j + 1 < NTILES) {
      #pragma unroll
      for (int p = 0; p < 16; ++p) {
        int i = tid + p*256;
        pre[p] = memv[(j+1)*(TILE_M*Esz/4) + (i >> 7)*128 + (i & 127)];
      }
    }

    f32x4 acc[2][2];
    #pragma unroll
    for (int mt = 0; mt < 2; ++mt)
      #pragma unroll
      for (int nt = 0; nt < 2; ++nt)
        acc[mt][nt] = (f32x4){0.f, 0.f, 0.f, 0.f};

    // K loop: 18 chunks of 32
    for (int kc = 0; kc < KP/32; ++kc) {
      int kg = kc*4 + quad;
      bf16x8 bfrag[2];
      #pragma unroll
      for (int nt = 0; nt < 2; ++nt) {
        int acol = lrow + 16*(2*w + nt);
        bfrag[nt] = *(const bf16x8*)&Wext[((size_t)kg*Asz + acol)*8];  // coalesced, L2-hot
      }
      bf16x8 afrag[2];
      #pragma unroll
      for (int mt = 0; mt < 2; ++mt) {
        int r = mt*16 + lrow;
        afrag[mt] = *(const bf16x8*)&Afull[r*KP + ((kg ^ (r & 7)) << 3)];
      }
      #pragma unroll
      for (int mt = 0; mt < 2; ++mt)
        #pragma unroll
        for (int nt = 0; nt < 2; ++nt)
          acc[mt][nt] = __builtin_amdgcn_mfma_f32_16x16x32_bf16(
              afrag[mt], bfrag[nt], acc[mt][nt], 0, 0, 0);
    }

    // energies: e_r = sum_a tanh(pm+pl+pq)*v_w  (C layout: col=lane&15, row=quad*4+reg)
    float partial[2][4];
    #pragma unroll
    for (int mt = 0; mt < 2; ++mt)
      #pragma unroll
      for (int rg = 0; rg < 4; ++rg) partial[mt][rg] = 0.f;
    #pragma unroll
    for (int nt = 0; nt < 2; ++nt) {
      int col = 16*(2*w + nt) + lrow;
      float vwc = s_vw[col], pqc = s_pq[col];
      #pragma unroll
      for (int mt = 0; mt < 2; ++mt)
        #pragma unroll
        for (int rg = 0; rg < 4; ++rg)
          partial[mt][rg] += tanhf(acc[mt][nt][rg] + pqc) * vwc;
    }
    #pragma unroll
    for (int off = 1; off < 16; off <<= 1)
      #pragma unroll
      for (int mt = 0; mt < 2; ++mt)
        #pragma unroll
        for (int rg = 0; rg < 4; ++rg)
          partial[mt][rg] += __shfl_xor(partial[mt][rg], off, 64);
    if (lrow == 0) {
      #pragma unroll
      for (int mt = 0; mt < 2; ++mt)
        #pragma unroll
        for (int rg = 0; rg < 4; ++rg)
          atomicAdd(&s_ebuf[mt*16 + quad*4 + rg], partial[mt][rg]);
    }
    __syncthreads();

    if (tid < TILE_M) {
      int t = tbase + j*TILE_M + tid;
      float al = s_ebuf[tid] + vb[0] + (float)mask[b*Tsz + t] * -1e25f;
      s_align[tid] = al;
      ws_align[b*Tsz + t] = al;
    }
    __syncthreads();

    // attention_output partial from the LDS tile (raw alignments, per reference)
    #pragma unroll
    for (int r = 0; r < TILE_M; ++r) {
      float al = s_align[r];
      int sw = ((k0 >> 3) ^ (r & 7));
      bf16x2 m = *(const bf16x2*)&Afull[r*KP + sw*8 + (k0 & 7)];
      outa0 += al * (float)m[0];
      outa1 += al * (float)m[1];
    }
    __syncthreads();   // protect Afull before next tile's convert
  }

  atomicAdd(&out[b*Esz + k0],     outa0);
  atomicAdd(&out[b*Esz + k0 + 1], outa1);
}

// ---------------- softmax over T per batch row ----------------
__global__ __launch_bounds__(256) void softmax_kernel(
    const float* __restrict__ ws_align, float* __restrict__ out_w)
{
  int b = blockIdx.x, tid = threadIdx.x;
  const float* row = ws_align + (size_t)b*Tsz;
  float vals[8];
  float lmax = -3.4e38f;
  #pragma unroll
  for (int i = 0; i < 8; ++i) { vals[i] = row[tid + i*256]; lmax = fmaxf(lmax, vals[i]); }
  #pragma unroll
  for (int off = 1; off < 64; off <<= 1) lmax = fmaxf(lmax, __shfl_xor(lmax, off, 64));
  __shared__ float smax[4], ssum[4];
  if ((tid & 63) == 0) smax[tid >> 6] = lmax;
  __syncthreads();
  float bmax = fmaxf(fmaxf(smax[0], smax[1]), fmaxf(smax[2], smax[3]));
  float lsum = 0.f;
  #pragma unroll
  for (int i = 0; i < 8; ++i) { vals[i] = __expf(vals[i] - bmax); lsum += vals[i]; }
  #pragma unroll
  for (int off = 1; off < 64; off <<= 1) lsum += __shfl_xor(lsum, off, 64);
  if ((tid & 63) == 0) ssum[tid >> 6] = lsum;
  __syncthreads();
  float inv = 1.f / (ssum[0] + ssum[1] + ssum[2] + ssum[3]);
  #pragma unroll
  for (int i = 0; i < 8; ++i) out_w[(size_t)b*Tsz + tid + i*256] = vals[i] * inv;
}

extern "C" void kernel_launch(void* const* d_in, const int* in_sizes, int n_in,
                              void* d_out, int out_size, void* d_ws, size_t ws_size,
                              hipStream_t stream) {
  const float* ah   = (const float*)d_in[0];
  const float* mem  = (const float*)d_in[1];
  const float* awc  = (const float*)d_in[2];
  const int*   mask = (const int*)d_in[3];
  const float* Wq   = (const float*)d_in[4];
  const float* Wm   = (const float*)d_in[5];
  const float* cw   = (const float*)d_in[6];
  const float* Wl   = (const float*)d_in[7];
  const float* vw   = (const float*)d_in[8];
  const float* vb   = (const float*)d_in[9];
  float* out = (float*)d_out;

  // ws layout: Wext bf16 [72][128][8] (147456 B) | pq f32 (32768 B) | align f32 [64][2048]
  bf16*  Wext = (bf16*)d_ws;
  float* pq   = (float*)((char*)d_ws + 147456);
  float* wsa  = (float*)((char*)d_ws + 180224);

  hipMemsetAsync(out, 0, Bsz*Esz*sizeof(float), stream);
  prep_kernel<<<dim3(224), 256, 0, stream>>>(Wm, cw, Wl, ah, Wq, Wext, pq);
  attn_main<<<dim3(Bsz*(Tsz/CHUNK)), 256, 0, stream>>>(mem, awc, mask, Wext, pq, vw, vb, out, wsa);
  softmax_kernel<<<dim3(Bsz), 256, 0, stream>>>(wsa, out + Bsz*Esz);
}

// Round 4
// 582.982 us; speedup vs baseline: 1.1448x; 1.1448x over previous
//
#include <hip/hip_runtime.h>

#define Bsz 64
#define Tsz 2048
#define Esz 512
#define Asz 128
#define Rsz 1024
#define KP  576        // 512 (E) + 62 conv taps + 2 zero pad
#define WROWS 16       // t-rows per wave
#define LPAD 520       // LDS row stride in elements (16-row bf16 tile, bank-spread)

typedef __bf16 bf16;
typedef __bf16 bf16x8 __attribute__((ext_vector_type(8)));
typedef float  f32x4  __attribute__((ext_vector_type(4)));

// Wext layout: [72 kgroups][128 a][8] bf16 -> element (a,k) at [k>>3][a][k&7].

// ---------------- prep ----------------
__global__ __launch_bounds__(256) void prep_kernel(
    const float* __restrict__ Wmem, const float* __restrict__ convw,
    const float* __restrict__ Wloc, const float* __restrict__ ah,
    const float* __restrict__ Wq, bf16* __restrict__ Wext,
    float* __restrict__ pq)
{
  __shared__ f32x4 red[256];
  int blk = blockIdx.x, tid = threadIdx.x;
  if (blk < 128) {
    int a = blk;
    #pragma unroll
    for (int e = tid; e < Esz; e += 256)
      Wext[(size_t)(e >> 3)*(Asz*8) + a*8 + (e & 7)] = (bf16)Wmem[e*Asz + a];
  } else if (blk < 160) {
    int idx = (blk - 128)*256 + tid;      // 8192 = 128 a x 64 j
    int a = idx >> 6, j = idx & 63;
    float u = 0.f;
    if (j < 62) {
      int c  = (j < 31) ? 0 : 1;
      int kk = (j < 31) ? j : j - 31;
      #pragma unroll
      for (int f = 0; f < 32; ++f)
        u += convw[f*62 + c*31 + kk] * Wloc[f*Asz + a];
    }
    Wext[(size_t)(64 + (j >> 3))*(Asz*8) + a*8 + (j & 7)] = (bf16)u;
  } else {
    int b  = blk - 160;
    int cg = tid & 31;
    int kg = tid >> 5;
    const float* ahb = ah + (size_t)b*Rsz;
    f32x4 s = (f32x4){0.f,0.f,0.f,0.f};
    int r0 = kg*128;
    for (int r = r0; r < r0 + 128; ++r) {
      float av = ahb[r];
      f32x4 wq = *(const f32x4*)&Wq[r*Asz + cg*4];
      s += av * wq;
    }
    red[tid] = s;
    __syncthreads();
    if (tid < 32) {
      f32x4 tot = red[tid];
      #pragma unroll
      for (int g = 1; g < 8; ++g) tot += red[g*32 + tid];
      *(f32x4*)&pq[b*Asz + tid*4] = tot;
    }
  }
}

__device__ __forceinline__ float tanh_fast(float x) {
  float ex = __expf(2.f * x);
  return 1.f - 2.f / (ex + 1.f);
}

// ---------------- main fused kernel: 1 wave per block, no barriers ----------------
__global__ __launch_bounds__(64) void attn_main(
    const float* __restrict__ memory, const float* __restrict__ awcat,
    const int* __restrict__ mask, const bf16* __restrict__ Wext,
    const float* __restrict__ pq, const float* __restrict__ vw,
    const float* __restrict__ vb, float* __restrict__ out,
    float* __restrict__ ws_align)
{
  __shared__ bf16 tile[WROWS * LPAD];    // 16640 B -> 9 blocks/CU

  int l    = threadIdx.x;                // 0..63
  int quad = l >> 4, lrow = l & 15;
  int b    = blockIdx.x >> 7;            // 128 chunks of 16 rows per batch
  int t0   = (blockIdx.x & 127) << 4;

  // --- early scalar prefetches (all L2-hot after first blocks) ---
  float pqv[8], vwv[8];
  #pragma unroll
  for (int nt = 0; nt < 8; ++nt) {
    pqv[nt] = pq[b*Asz + 16*nt + lrow];
    vwv[nt] = vw[16*nt + lrow];
  }
  int maskv[4];
  #pragma unroll
  for (int rg = 0; rg < 4; ++rg)
    maskv[rg] = mask[b*Tsz + t0 + quad*4 + rg];
  float vb0 = vb[0];

  // im2col'd location A-fragments for K-chunks 16,17 (k = 512 + jloc)
  const float* aw = awcat + (size_t)b*2*Tsz;
  float awv[2][8];
  #pragma unroll
  for (int g = 0; g < 2; ++g)
    #pragma unroll
    for (int j = 0; j < 8; ++j) {
      int jloc = g*32 + quad*8 + j;
      float v = 0.f;
      if (jloc < 62) {
        int c  = (jloc < 31) ? 0 : 1;
        int kk = (jloc < 31) ? jloc : jloc - 31;
        int t  = t0 + lrow + kk - 15;
        if (t >= 0 && t < Tsz) v = aw[c*Tsz + t];
      }
      awv[g][j] = v;
    }

  // --- K loop: A direct from global (fp32->bf16 in regs), B from L2-hot Wext ---
  const float* ap = memory + ((size_t)(b*Tsz) + t0 + lrow)*Esz + quad*8;
  const bf16*  bp = Wext + ((size_t)quad*Asz + lrow)*8;

  f32x4 acc[8];
  #pragma unroll
  for (int nt = 0; nt < 8; ++nt) acc[nt] = (f32x4){0.f,0.f,0.f,0.f};

  #pragma unroll
  for (int kc = 0; kc < 16; ++kc) {
    f32x4 aA = *(const f32x4*)(ap + kc*32);
    f32x4 aB = *(const f32x4*)(ap + kc*32 + 4);
    bf16x8 bfr[8];
    #pragma unroll
    for (int nt = 0; nt < 8; ++nt)
      bfr[nt] = *(const bf16x8*)(bp + (size_t)kc*4096 + nt*128);
    bf16x8 af;
    #pragma unroll
    for (int j = 0; j < 4; ++j) { af[j] = (bf16)aA[j]; af[4+j] = (bf16)aB[j]; }
    *(bf16x8*)&tile[lrow*LPAD + kc*32 + quad*8] = af;   // epilogue copy
    #pragma unroll
    for (int nt = 0; nt < 8; ++nt)
      acc[nt] = __builtin_amdgcn_mfma_f32_16x16x32_bf16(af, bfr[nt], acc[nt], 0, 0, 0);
  }
  // location K-chunks 16,17
  #pragma unroll
  for (int g = 0; g < 2; ++g) {
    bf16x8 bfr[8];
    #pragma unroll
    for (int nt = 0; nt < 8; ++nt)
      bfr[nt] = *(const bf16x8*)(bp + (size_t)(16+g)*4096 + nt*128);
    bf16x8 af;
    #pragma unroll
    for (int j = 0; j < 8; ++j) af[j] = (bf16)awv[g][j];
    #pragma unroll
    for (int nt = 0; nt < 8; ++nt)
      acc[nt] = __builtin_amdgcn_mfma_f32_16x16x32_bf16(af, bfr[nt], acc[nt], 0, 0, 0);
  }

  // --- energies: E[m] = sum_a tanh(pm+pl+pq)*vw  (C: col=lrow -> a=16nt+lrow, row=quad*4+rg)
  float partial[4];
  #pragma unroll
  for (int rg = 0; rg < 4; ++rg) partial[rg] = 0.f;
  #pragma unroll
  for (int nt = 0; nt < 8; ++nt)
    #pragma unroll
    for (int rg = 0; rg < 4; ++rg)
      partial[rg] += tanh_fast(acc[nt][rg] + pqv[nt]) * vwv[nt];
  #pragma unroll
  for (int off = 1; off < 16; off <<= 1)
    #pragma unroll
    for (int rg = 0; rg < 4; ++rg)
      partial[rg] += __shfl_xor(partial[rg], off, 64);

  float alignv[4];
  #pragma unroll
  for (int rg = 0; rg < 4; ++rg)
    alignv[rg] = partial[rg] + vb0 + (float)maskv[rg] * -1e25f;
  if (lrow == 0) {
    #pragma unroll
    for (int rg = 0; rg < 4; ++rg)
      ws_align[b*Tsz + t0 + quad*4 + rg] = alignv[rg];
  }

  __syncthreads();   // single wave: drains LDS writes before epilogue reads

  // --- attention_output partial: out[b,e] += sum_r align[r]*mem[r,e], lane owns 8 e-cols
  float outv[8];
  #pragma unroll
  for (int j = 0; j < 8; ++j) outv[j] = 0.f;
  #pragma unroll
  for (int r = 0; r < WROWS; ++r) {
    float al = __shfl(alignv[r & 3], (r >> 2) * 16, 64);
    bf16x8 m = *(const bf16x8*)&tile[r*LPAD + l*8];
    #pragma unroll
    for (int j = 0; j < 8; ++j) outv[j] += al * (float)m[j];
  }
  float* op = out + b*Esz + l*8;
  #pragma unroll
  for (int j = 0; j < 8; ++j) atomicAdd(op + j, outv[j]);
}

// ---------------- softmax over T per batch row ----------------
__global__ __launch_bounds__(256) void softmax_kernel(
    const float* __restrict__ ws_align, float* __restrict__ out_w)
{
  int b = blockIdx.x, tid = threadIdx.x;
  const float* row = ws_align + (size_t)b*Tsz;
  float vals[8];
  float lmax = -3.4e38f;
  #pragma unroll
  for (int i = 0; i < 8; ++i) { vals[i] = row[tid + i*256]; lmax = fmaxf(lmax, vals[i]); }
  #pragma unroll
  for (int off = 1; off < 64; off <<= 1) lmax = fmaxf(lmax, __shfl_xor(lmax, off, 64));
  __shared__ float smax[4], ssum[4];
  if ((tid & 63) == 0) smax[tid >> 6] = lmax;
  __syncthreads();
  float bmax = fmaxf(fmaxf(smax[0], smax[1]), fmaxf(smax[2], smax[3]));
  float lsum = 0.f;
  #pragma unroll
  for (int i = 0; i < 8; ++i) { vals[i] = __expf(vals[i] - bmax); lsum += vals[i]; }
  #pragma unroll
  for (int off = 1; off < 64; off <<= 1) lsum += __shfl_xor(lsum, off, 64);
  if ((tid & 63) == 0) ssum[tid >> 6] = lsum;
  __syncthreads();
  float inv = 1.f / (ssum[0] + ssum[1] + ssum[2] + ssum[3]);
  #pragma unroll
  for (int i = 0; i < 8; ++i) out_w[(size_t)b*Tsz + tid + i*256] = vals[i] * inv;
}

extern "C" void kernel_launch(void* const* d_in, const int* in_sizes, int n_in,
                              void* d_out, int out_size, void* d_ws, size_t ws_size,
                              hipStream_t stream) {
  const float* ah   = (const float*)d_in[0];
  const float* mem  = (const float*)d_in[1];
  const float* awc  = (const float*)d_in[2];
  const int*   mask = (const int*)d_in[3];
  const float* Wq   = (const float*)d_in[4];
  const float* Wm   = (const float*)d_in[5];
  const float* cw   = (const float*)d_in[6];
  const float* Wl   = (const float*)d_in[7];
  const float* vw   = (const float*)d_in[8];
  const float* vb   = (const float*)d_in[9];
  float* out = (float*)d_out;

  // ws layout: Wext bf16 [72][128][8] (147456 B) | pq f32 (32768 B) | align f32 [64][2048]
  bf16*  Wext = (bf16*)d_ws;
  float* pq   = (float*)((char*)d_ws + 147456);
  float* wsa  = (float*)((char*)d_ws + 180224);

  hipMemsetAsync(out, 0, Bsz*Esz*sizeof(float), stream);
  prep_kernel<<<dim3(224), 256, 0, stream>>>(Wm, cw, Wl, ah, Wq, Wext, pq);
  attn_main<<<dim3(Bsz*(Tsz/WROWS)), 64, 0, stream>>>(mem, awc, mask, Wext, pq, vw, vb, out, wsa);
  softmax_kernel<<<dim3(Bsz), 256, 0, stream>>>(wsa, out + Bsz*Esz);
}

// Round 5
// 466.969 us; speedup vs baseline: 1.4293x; 1.2484x over previous
//
#include <hip/hip_runtime.h>

#define Bsz 64
#define Tsz 2048
#define Esz 512
#define Asz 128
#define Rsz 1024
#define KP  576      // 512 (E) + 62 conv taps + 2 zero pad
#define TILE_M 32

typedef __bf16 bf16;
typedef __bf16 bf16x8 __attribute__((ext_vector_type(8)));
typedef __bf16 bf16x4 __attribute__((ext_vector_type(4)));
typedef __bf16 bf16x2 __attribute__((ext_vector_type(2)));
typedef float  f32x4  __attribute__((ext_vector_type(4)));

// Wext layout: [72 kgroups][128 a][8] bf16 -> element (a,k) at [k>>3][a][k&7].
// B-fragment wave-load = 64 lanes x 16 B spanning 4 kgroups x 16 acols -> 8 dense
// 128B lines (vs 16 scattered lines in the old [a][k] layout).

// ---------------- prep ----------------
__global__ __launch_bounds__(256) void prep_kernel(
    const float* __restrict__ Wmem, const float* __restrict__ convw,
    const float* __restrict__ Wloc, const float* __restrict__ ah,
    const float* __restrict__ Wq, bf16* __restrict__ Wext,
    float* __restrict__ pq)
{
  __shared__ f32x4 red[256];
  int blk = blockIdx.x, tid = threadIdx.x;
  if (blk < 128) {
    int a = blk;
    #pragma unroll
    for (int e = tid; e < Esz; e += 256)
      Wext[(size_t)(e >> 3)*(Asz*8) + a*8 + (e & 7)] = (bf16)Wmem[e*Asz + a];
  } else if (blk < 160) {
    int idx = (blk - 128)*256 + tid;      // 8192 = 128 a x 64 j
    int a = idx >> 6, j = idx & 63;
    float u = 0.f;
    if (j < 62) {
      int c  = (j < 31) ? 0 : 1;
      int kk = (j < 31) ? j : j - 31;
      #pragma unroll
      for (int f = 0; f < 32; ++f)
        u += convw[f*62 + c*31 + kk] * Wloc[f*Asz + a];
    }
    Wext[(size_t)(64 + (j >> 3))*(Asz*8) + a*8 + (j & 7)] = (bf16)u;
  } else {
    int b  = blk - 160;
    int cg = tid & 31;
    int kg = tid >> 5;
    const float* ahb = ah + (size_t)b*Rsz;
    f32x4 s = (f32x4){0.f,0.f,0.f,0.f};
    int r0 = kg*128;
    for (int r = r0; r < r0 + 128; ++r) {
      float av = ahb[r];
      f32x4 wq = *(const f32x4*)&Wq[r*Asz + cg*4];
      s += av * wq;
    }
    red[tid] = s;
    __syncthreads();
    if (tid < 32) {
      f32x4 tot = red[tid];
      #pragma unroll
      for (int g = 1; g < 8; ++g) tot += red[g*32 + tid];
      *(f32x4*)&pq[b*Asz + tid*4] = tot;
    }
  }
}

__device__ __forceinline__ float tanh_fast(float x) {
  float ex = __expf(2.f * x);
  return 1.f - 2.f / (ex + 1.f);
}

// ---------------- main fused kernel (R2 structure + coalesced Wext) ----------------
__global__ __launch_bounds__(256) void attn_main(
    const float* __restrict__ memory, const float* __restrict__ awcat,
    const int* __restrict__ mask, const bf16* __restrict__ Wext,
    const float* __restrict__ pq, const float* __restrict__ vw,
    const float* __restrict__ vb, float* __restrict__ out,
    float* __restrict__ ws_align)
{
  __shared__ bf16  Afull[TILE_M * KP];   // 36864 B, XOR-chunk swizzled
  __shared__ float s_pq[Asz];
  __shared__ float s_vw[Asz];
  __shared__ float s_ebuf[TILE_M];
  __shared__ float s_align[TILE_M];

  int tid = threadIdx.x;
  int b  = blockIdx.x >> 6;
  int t0 = (blockIdx.x & 63) << 5;

  // stage memory tile fp32 -> bf16 LDS (coalesced float4 loads)
  const float4* memv = (const float4*)(memory + (size_t)(b*Tsz + t0)*Esz);
  #pragma unroll
  for (int i = tid; i < TILE_M*(Esz/4); i += 256) {
    int r = i >> 7, c4 = i & 127;
    float4 v = memv[r*128 + c4];
    int k = c4 * 4;
    int sw = (k >> 3) ^ (r & 7);
    int base = r*KP + sw*8 + (k & 7);
    bf16x4 p; p[0]=(bf16)v.x; p[1]=(bf16)v.y; p[2]=(bf16)v.z; p[3]=(bf16)v.w;
    *(bf16x4*)&Afull[base] = p;
  }
  // stage im2col'd aw window into K columns 512..575
  const float* aw = awcat + (size_t)b*2*Tsz;
  #pragma unroll
  for (int i = tid; i < TILE_M*64; i += 256) {
    int r = i >> 6, j = i & 63;
    float val = 0.f;
    if (j < 62) {
      int c  = (j < 31) ? 0 : 1;
      int kk = (j < 31) ? j : j - 31;
      int t  = t0 + r + kk - 15;
      if (t >= 0 && t < Tsz) val = aw[c*Tsz + t];
    }
    int k = Esz + j;
    int sw = (k >> 3) ^ (r & 7);
    Afull[r*KP + sw*8 + (k & 7)] = (bf16)val;
  }
  if (tid < Asz) { s_pq[tid] = pq[b*Asz + tid]; s_vw[tid] = vw[tid]; }
  if (tid < TILE_M) s_ebuf[tid] = 0.f;
  __syncthreads();

  int w = tid >> 6, l = tid & 63;
  int quad = l >> 4, lrow = l & 15;

  f32x4 acc[2][2];
  #pragma unroll
  for (int mt = 0; mt < 2; ++mt)
    #pragma unroll
    for (int nt = 0; nt < 2; ++nt)
      acc[mt][nt] = (f32x4){0.f, 0.f, 0.f, 0.f};

  // K loop: 18 chunks of 32 (512 memory + 64 location)
  for (int kc = 0; kc < KP/32; ++kc) {
    int kg = kc*4 + quad;
    bf16x8 bfrag[2];
    #pragma unroll
    for (int nt = 0; nt < 2; ++nt) {
      int acol = lrow + 16*(2*w + nt);
      bfrag[nt] = *(const bf16x8*)&Wext[((size_t)kg*Asz + acol)*8];  // dense, L2-hot
    }
    bf16x8 afrag[2];
    #pragma unroll
    for (int mt = 0; mt < 2; ++mt) {
      int r = mt*16 + lrow;
      afrag[mt] = *(const bf16x8*)&Afull[r*KP + ((kg ^ (r & 7)) << 3)];
    }
    #pragma unroll
    for (int mt = 0; mt < 2; ++mt)
      #pragma unroll
      for (int nt = 0; nt < 2; ++nt)
        acc[mt][nt] = __builtin_amdgcn_mfma_f32_16x16x32_bf16(
            afrag[mt], bfrag[nt], acc[mt][nt], 0, 0, 0);
  }

  // energies: e_r = sum_a tanh(pm+pl+pq)*v_w   (C layout: col=lane&15, row=quad*4+reg)
  float partial[2][4];
  #pragma unroll
  for (int mt = 0; mt < 2; ++mt)
    #pragma unroll
    for (int rg = 0; rg < 4; ++rg) partial[mt][rg] = 0.f;
  #pragma unroll
  for (int nt = 0; nt < 2; ++nt) {
    int col = 16*(2*w + nt) + lrow;
    float vwc = s_vw[col], pqc = s_pq[col];
    #pragma unroll
    for (int mt = 0; mt < 2; ++mt)
      #pragma unroll
      for (int rg = 0; rg < 4; ++rg)
        partial[mt][rg] += tanh_fast(acc[mt][nt][rg] + pqc) * vwc;
  }
  #pragma unroll
  for (int off = 1; off < 16; off <<= 1)
    #pragma unroll
    for (int mt = 0; mt < 2; ++mt)
      #pragma unroll
      for (int rg = 0; rg < 4; ++rg)
        partial[mt][rg] += __shfl_xor(partial[mt][rg], off, 64);
  if (lrow == 0) {
    #pragma unroll
    for (int mt = 0; mt < 2; ++mt)
      #pragma unroll
      for (int rg = 0; rg < 4; ++rg)
        atomicAdd(&s_ebuf[mt*16 + quad*4 + rg], partial[mt][rg]);
  }
  __syncthreads();

  if (tid < TILE_M) {
    int t = t0 + tid;
    float al = s_ebuf[tid] + vb[0] + (float)mask[b*Tsz + t] * -1e25f;
    s_align[tid] = al;
    ws_align[b*Tsz + t] = al;
  }
  __syncthreads();

  // attention_output partial: out[b,e] += sum_r align[r] * mem[r,e]  (reuse LDS tile)
  int k0 = tid * 2;           // paired adjacent columns -> 4B LDS reads
  float a0 = 0.f, a1 = 0.f;
  #pragma unroll
  for (int r = 0; r < TILE_M; ++r) {
    float al = s_align[r];
    int sw = ((k0 >> 3) ^ (r & 7));
    bf16x2 m = *(const bf16x2*)&Afull[r*KP + sw*8 + (k0 & 7)];
    a0 += al * (float)m[0];
    a1 += al * (float)m[1];
  }
  atomicAdd(&out[b*Esz + k0],     a0);
  atomicAdd(&out[b*Esz + k0 + 1], a1);
}

// ---------------- softmax over T per batch row ----------------
__global__ __launch_bounds__(256) void softmax_kernel(
    const float* __restrict__ ws_align, float* __restrict__ out_w)
{
  int b = blockIdx.x, tid = threadIdx.x;
  const float* row = ws_align + (size_t)b*Tsz;
  float vals[8];
  float lmax = -3.4e38f;
  #pragma unroll
  for (int i = 0; i < 8; ++i) { vals[i] = row[tid + i*256]; lmax = fmaxf(lmax, vals[i]); }
  #pragma unroll
  for (int off = 1; off < 64; off <<= 1) lmax = fmaxf(lmax, __shfl_xor(lmax, off, 64));
  __shared__ float smax[4], ssum[4];
  if ((tid & 63) == 0) smax[tid >> 6] = lmax;
  __syncthreads();
  float bmax = fmaxf(fmaxf(smax[0], smax[1]), fmaxf(smax[2], smax[3]));
  float lsum = 0.f;
  #pragma unroll
  for (int i = 0; i < 8; ++i) { vals[i] = __expf(vals[i] - bmax); lsum += vals[i]; }
  #pragma unroll
  for (int off = 1; off < 64; off <<= 1) lsum += __shfl_xor(lsum, off, 64);
  if ((tid & 63) == 0) ssum[tid >> 6] = lsum;
  __syncthreads();
  float inv = 1.f / (ssum[0] + ssum[1] + ssum[2] + ssum[3]);
  #pragma unroll
  for (int i = 0; i < 8; ++i) out_w[(size_t)b*Tsz + tid + i*256] = vals[i] * inv;
}

extern "C" void kernel_launch(void* const* d_in, const int* in_sizes, int n_in,
                              void* d_out, int out_size, void* d_ws, size_t ws_size,
                              hipStream_t stream) {
  const float* ah   = (const float*)d_in[0];
  const float* mem  = (const float*)d_in[1];
  const float* awc  = (const float*)d_in[2];
  const int*   mask = (const int*)d_in[3];
  const float* Wq   = (const float*)d_in[4];
  const float* Wm   = (const float*)d_in[5];
  const float* cw   = (const float*)d_in[6];
  const float* Wl   = (const float*)d_in[7];
  const float* vw   = (const float*)d_in[8];
  const float* vb   = (const float*)d_in[9];
  float* out = (float*)d_out;

  // ws layout: Wext bf16 [72][128][8] (147456 B) | pq f32 (32768 B) | align f32 [64][2048]
  bf16*  Wext = (bf16*)d_ws;
  float* pq   = (float*)((char*)d_ws + 147456);
  float* wsa  = (float*)((char*)d_ws + 180224);

  hipMemsetAsync(out, 0, Bsz*Esz*sizeof(float), stream);
  prep_kernel<<<dim3(224), 256, 0, stream>>>(Wm, cw, Wl, ah, Wq, Wext, pq);
  attn_main<<<dim3(Bsz*(Tsz/TILE_M)), 256, 0, stream>>>(mem, awc, mask, Wext, pq, vw, vb, out, wsa);
  softmax_kernel<<<dim3(Bsz), 256, 0, stream>>>(wsa, out + Bsz*Esz);
}

// Round 6
// 457.004 us; speedup vs baseline: 1.4604x; 1.0218x over previous
//
#include <hip/hip_runtime.h>

#define Bsz 64
#define Tsz 2048
#define Esz 512
#define Asz 128
#define Rsz 1024
#define KP  576      // 512 (E) + 62 conv taps + 2 zero pad
#define TILE_M 16

typedef __bf16 bf16;
typedef __bf16 bf16x8 __attribute__((ext_vector_type(8)));
typedef __bf16 bf16x4 __attribute__((ext_vector_type(4)));
typedef __bf16 bf16x2 __attribute__((ext_vector_type(2)));
typedef float  f32x4  __attribute__((ext_vector_type(4)));

// Wext layout: [72 kgroups][128 a][8] bf16 -> element (a,k) at [k>>3][a][k&7].
// B-fragment wave-load = 64 lanes x 16 B spanning 4 kgroups x 16 acols -> 8 dense
// 128B lines.

// ---------------- prep ----------------
__global__ __launch_bounds__(256) void prep_kernel(
    const float* __restrict__ Wmem, const float* __restrict__ convw,
    const float* __restrict__ Wloc, const float* __restrict__ ah,
    const float* __restrict__ Wq, bf16* __restrict__ Wext,
    float* __restrict__ pq)
{
  __shared__ f32x4 red[256];
  int blk = blockIdx.x, tid = threadIdx.x;
  if (blk < 128) {
    int a = blk;
    #pragma unroll
    for (int e = tid; e < Esz; e += 256)
      Wext[(size_t)(e >> 3)*(Asz*8) + a*8 + (e & 7)] = (bf16)Wmem[e*Asz + a];
  } else if (blk < 160) {
    int idx = (blk - 128)*256 + tid;      // 8192 = 128 a x 64 j
    int a = idx >> 6, j = idx & 63;
    float u = 0.f;
    if (j < 62) {
      int c  = (j < 31) ? 0 : 1;
      int kk = (j < 31) ? j : j - 31;
      #pragma unroll
      for (int f = 0; f < 32; ++f)
        u += convw[f*62 + c*31 + kk] * Wloc[f*Asz + a];
    }
    Wext[(size_t)(64 + (j >> 3))*(Asz*8) + a*8 + (j & 7)] = (bf16)u;
  } else {
    int b  = blk - 160;
    int cg = tid & 31;
    int kg = tid >> 5;
    const float* ahb = ah + (size_t)b*Rsz;
    f32x4 s = (f32x4){0.f,0.f,0.f,0.f};
    int r0 = kg*128;
    for (int r = r0; r < r0 + 128; ++r) {
      float av = ahb[r];
      f32x4 wq = *(const f32x4*)&Wq[r*Asz + cg*4];
      s += av * wq;
    }
    red[tid] = s;
    __syncthreads();
    if (tid < 32) {
      f32x4 tot = red[tid];
      #pragma unroll
      for (int g = 1; g < 8; ++g) tot += red[g*32 + tid];
      *(f32x4*)&pq[b*Asz + tid*4] = tot;
    }
  }
}

__device__ __forceinline__ float tanh_fast(float x) {
  float ex = __expf(2.f * x);
  return 1.f - 2.f / (ex + 1.f);
}

// ---------------- main fused kernel (16-row tiles, 8 blocks/CU) ----------------
__global__ __launch_bounds__(256, 6) void attn_main(
    const float* __restrict__ memory, const float* __restrict__ awcat,
    const int* __restrict__ mask, const bf16* __restrict__ Wext,
    const float* __restrict__ pq, const float* __restrict__ vw,
    const float* __restrict__ vb, float* __restrict__ out,
    float* __restrict__ ws_align)
{
  __shared__ bf16  Afull[TILE_M * KP];   // 18432 B, XOR-chunk swizzled
  __shared__ float s_pq[Asz];
  __shared__ float s_vw[Asz];
  __shared__ float s_ebuf[TILE_M];
  __shared__ float s_align[TILE_M];

  int tid = threadIdx.x;
  int b  = blockIdx.x >> 7;              // 128 chunks of 16 rows per batch
  int t0 = (blockIdx.x & 127) << 4;

  // stage memory tile fp32 -> bf16 LDS (coalesced float4 loads, 8 per thread)
  const float4* memv = (const float4*)(memory + (size_t)(b*Tsz + t0)*Esz);
  #pragma unroll
  for (int p = 0; p < 8; ++p) {
    int i = tid + p*256;
    int r = i >> 7, c4 = i & 127;
    float4 v = memv[r*128 + c4];
    int k = c4 * 4;
    int sw = (k >> 3) ^ (r & 7);
    int base = r*KP + sw*8 + (k & 7);
    bf16x4 pk; pk[0]=(bf16)v.x; pk[1]=(bf16)v.y; pk[2]=(bf16)v.z; pk[3]=(bf16)v.w;
    *(bf16x4*)&Afull[base] = pk;
  }
  // stage im2col'd aw window into K columns 512..575 (16x64 = 4 per thread)
  const float* aw = awcat + (size_t)b*2*Tsz;
  #pragma unroll
  for (int p = 0; p < 4; ++p) {
    int i = tid + p*256;
    int r = i >> 6, j = i & 63;
    float val = 0.f;
    if (j < 62) {
      int c  = (j < 31) ? 0 : 1;
      int kk = (j < 31) ? j : j - 31;
      int t  = t0 + r + kk - 15;
      if (t >= 0 && t < Tsz) val = aw[c*Tsz + t];
    }
    int k = Esz + j;
    int sw = (k >> 3) ^ (r & 7);
    Afull[r*KP + sw*8 + (k & 7)] = (bf16)val;
  }
  if (tid < Asz) { s_pq[tid] = pq[b*Asz + tid]; s_vw[tid] = vw[tid]; }
  if (tid < TILE_M) s_ebuf[tid] = 0.f;
  __syncthreads();

  int w = tid >> 6, l = tid & 63;
  int quad = l >> 4, lrow = l & 15;

  f32x4 acc[2];
  acc[0] = (f32x4){0.f, 0.f, 0.f, 0.f};
  acc[1] = (f32x4){0.f, 0.f, 0.f, 0.f};

  // K loop: 18 chunks of 32 (512 memory + 64 location)
  for (int kc = 0; kc < KP/32; ++kc) {
    int kg = kc*4 + quad;
    bf16x8 bfrag[2];
    #pragma unroll
    for (int nt = 0; nt < 2; ++nt) {
      int acol = lrow + 16*(2*w + nt);
      bfrag[nt] = *(const bf16x8*)&Wext[((size_t)kg*Asz + acol)*8];  // dense, L2-hot
    }
    bf16x8 afrag = *(const bf16x8*)&Afull[lrow*KP + ((kg ^ (lrow & 7)) << 3)];
    #pragma unroll
    for (int nt = 0; nt < 2; ++nt)
      acc[nt] = __builtin_amdgcn_mfma_f32_16x16x32_bf16(afrag, bfrag[nt], acc[nt], 0, 0, 0);
  }

  // energies: e_r = sum_a tanh(pm+pl+pq)*v_w   (C layout: col=lane&15, row=quad*4+reg)
  float partial[4];
  #pragma unroll
  for (int rg = 0; rg < 4; ++rg) partial[rg] = 0.f;
  #pragma unroll
  for (int nt = 0; nt < 2; ++nt) {
    int col = 16*(2*w + nt) + lrow;
    float vwc = s_vw[col], pqc = s_pq[col];
    #pragma unroll
    for (int rg = 0; rg < 4; ++rg)
      partial[rg] += tanh_fast(acc[nt][rg] + pqc) * vwc;
  }
  #pragma unroll
  for (int off = 1; off < 16; off <<= 1)
    #pragma unroll
    for (int rg = 0; rg < 4; ++rg)
      partial[rg] += __shfl_xor(partial[rg], off, 64);
  if (lrow == 0) {
    #pragma unroll
    for (int rg = 0; rg < 4; ++rg)
      atomicAdd(&s_ebuf[quad*4 + rg], partial[rg]);
  }
  __syncthreads();

  if (tid < TILE_M) {
    int t = t0 + tid;
    float al = s_ebuf[tid] + vb[0] + (float)mask[b*Tsz + t] * -1e25f;
    s_align[tid] = al;
    ws_align[b*Tsz + t] = al;
  }
  __syncthreads();

  // attention_output partial: out[b,e] += sum_r align[r] * mem[r,e]  (reuse LDS tile)
  int k0 = tid * 2;           // paired adjacent columns -> 4B LDS reads
  float a0 = 0.f, a1 = 0.f;
  #pragma unroll
  for (int r = 0; r < TILE_M; ++r) {
    float al = s_align[r];
    int sw = ((k0 >> 3) ^ (r & 7));
    bf16x2 m = *(const bf16x2*)&Afull[r*KP + sw*8 + (k0 & 7)];
    a0 += al * (float)m[0];
    a1 += al * (float)m[1];
  }
  atomicAdd(&out[b*Esz + k0],     a0);
  atomicAdd(&out[b*Esz + k0 + 1], a1);
}

// ---------------- softmax over T per batch row ----------------
__global__ __launch_bounds__(256) void softmax_kernel(
    const float* __restrict__ ws_align, float* __restrict__ out_w)
{
  int b = blockIdx.x, tid = threadIdx.x;
  const float* row = ws_align + (size_t)b*Tsz;
  float vals[8];
  float lmax = -3.4e38f;
  #pragma unroll
  for (int i = 0; i < 8; ++i) { vals[i] = row[tid + i*256]; lmax = fmaxf(lmax, vals[i]); }
  #pragma unroll
  for (int off = 1; off < 64; off <<= 1) lmax = fmaxf(lmax, __shfl_xor(lmax, off, 64));
  __shared__ float smax[4], ssum[4];
  if ((tid & 63) == 0) smax[tid >> 6] = lmax;
  __syncthreads();
  float bmax = fmaxf(fmaxf(smax[0], smax[1]), fmaxf(smax[2], smax[3]));
  float lsum = 0.f;
  #pragma unroll
  for (int i = 0; i < 8; ++i) { vals[i] = __expf(vals[i] - bmax); lsum += vals[i]; }
  #pragma unroll
  for (int off = 1; off < 64; off <<= 1) lsum += __shfl_xor(lsum, off, 64);
  if ((tid & 63) == 0) ssum[tid >> 6] = lsum;
  __syncthreads();
  float inv = 1.f / (ssum[0] + ssum[1] + ssum[2] + ssum[3]);
  #pragma unroll
  for (int i = 0; i < 8; ++i) out_w[(size_t)b*Tsz + tid + i*256] = vals[i] * inv;
}

extern "C" void kernel_launch(void* const* d_in, const int* in_sizes, int n_in,
                              void* d_out, int out_size, void* d_ws, size_t ws_size,
                              hipStream_t stream) {
  const float* ah   = (const float*)d_in[0];
  const float* mem  = (const float*)d_in[1];
  const float* awc  = (const float*)d_in[2];
  const int*   mask = (const int*)d_in[3];
  const float* Wq   = (const float*)d_in[4];
  const float* Wm   = (const float*)d_in[5];
  const float* cw   = (const float*)d_in[6];
  const float* Wl   = (const float*)d_in[7];
  const float* vw   = (const float*)d_in[8];
  const float* vb   = (const float*)d_in[9];
  float* out = (float*)d_out;

  // ws layout: Wext bf16 [72][128][8] (147456 B) | pq f32 (32768 B) | align f32 [64][2048]
  bf16*  Wext = (bf16*)d_ws;
  float* pq   = (float*)((char*)d_ws + 147456);
  float* wsa  = (float*)((char*)d_ws + 180224);

  hipMemsetAsync(out, 0, Bsz*Esz*sizeof(float), stream);
  prep_kernel<<<dim3(224), 256, 0, stream>>>(Wm, cw, Wl, ah, Wq, Wext, pq);
  attn_main<<<dim3(Bsz*(Tsz/TILE_M)), 256, 0, stream>>>(mem, awc, mask, Wext, pq, vw, vb, out, wsa);
  softmax_kernel<<<dim3(Bsz), 256, 0, stream>>>(wsa, out + Bsz*Esz);
}